// Round 7
// baseline (923.879 us; speedup 1.0000x reference)
//
#include <hip/hip_runtime.h>

// NodeDenoisingADMM: N=20000, FEAT=64, K=4, NNZ=320000, NU=2.0, GAMMA=1.0, J=3
// 14 scan iterations, output = final U (N,FEAT) fp32.
//
// State reduction (GAMMA=1): carried state is v alone.
//   S_t = W_k @ U_t ; Y_t = S_t + v_{t-1} ; Z_t = soft(S_t + Y_t, nu_k d)
//   v_t = Y_t - Z_t ; U_{t+1} = (dm*F - sum_k W_k v_k)/(dm+1), dm = d*mask^2
//
// Node-major CSR: rowid = n*K + k. Edge meta packed in 4 B:
//   [31] sign | [30:26] exp5 (bias 96, 0 => value 0) | [25:17] mant9 (RNE)
//   | [16:15] k | [14:0] col       (rel err 2^-11 < bf16 operand err)
//
// HISTORY: R1 k-phase wtv: REGRESS. R2 meta pipeline: WIN (keep).
// R3 NT loads: REGRESS (forced L2 miss on latency chains). R4/R5 gather
// pipeline: REGRESS (+80 VGPR occupancy step; TLP > ILP here). R6 scatter
// atomic-MLP: REGRESS (+12 us) -> PROVES scatter was traffic-bound, not
// atomic-latency-bound (110 MB: 8x-replicated rows read = 41 MB + bounce).
// R7: two-pass bucket partition. hist_stage reads rows/cols/vals ONCE,
// packs pk, partitions into 8 XCD buckets (LDS rank + 1 global atomic per
// block per bucket) -> staged pk(u32)+rk16(u16). scatter2 reads staging
// contiguously, cursor-atomics + cmeta writes stay XCD-local (bucket =
// blockIdx%8). Scatter-path traffic ~110 -> ~38 MB. Staging aliases V_bf
// (dead until first spmm). Within-row order changes (already arbitrary).
// KEPT: LAST-only fp32 U store (write elim 13x5.12 MB).

constexpr int N_    = 20000;
constexpr int FEAT_ = 64;
constexpr int K_    = 4;
constexpr int NNZ_  = 320000;
constexpr int NF    = N_ * FEAT_;     // 1,280,000
constexpr int KN    = K_ * N_;        // 80,000 CSR rows
constexpr int NEDGE = K_ * NNZ_;      // 1,280,000
constexpr int NITER = 14;
constexpr int BLK   = 256;
constexpr int NSB   = (KN + 255) / 256;  // 313 scan blocks
constexpr int NCPY  = 8;                 // hist privatization copies
constexpr int NXCD  = 8;
constexpr int NPB   = N_ / NXCD;         // 2500 rows per bucket
constexpr int EPV   = 2048;              // edges per scatter2 block
constexpr int CAP   = 81 * EPV;          // 165,888 bucket capacity (~160k+15sigma)
constexpr int NCH   = CAP / EPV;         // 81 chunks per bucket

constexpr int R_SP  = 10;                          // CSR rows/wave, spmm
constexpr int NB_SP = ((KN + R_SP - 1) / R_SP + 3) / 4;   // 2000 blocks
constexpr int R_WT  = 4;                           // nodes/wave, wtv
constexpr int NB_WT = ((N_ + R_WT - 1) / R_WT + 3) / 4;   // 1250 blocks

__constant__ float c_nu[4] = {0.0f, 2.0f, 0.5f, 0.125f};

__device__ __forceinline__ float softf(float x, float t) {
    float a = fabsf(x) - t;
    a = a > 0.0f ? a : 0.0f;
    return copysignf(a, x);
}

__device__ __forceinline__ float bf2f(unsigned short u) {
    union { unsigned int i; float f; } x;
    x.i = ((unsigned int)u) << 16;
    return x.f;
}
__device__ __forceinline__ unsigned short f2bf(float f) {   // RNE
    union { float f; unsigned int i; } x;
    x.f = f;
    unsigned int r = x.i + 0x7FFFu + ((x.i >> 16) & 1u);
    return (unsigned short)(r >> 16);
}

__device__ __forceinline__ void decode_meta(unsigned int p, int& c, float& v) {
    c = (int)((p >> 15) & 3u) * N_ + (int)(p & 0x7FFFu);
    unsigned int e5 = (p >> 26) & 0x1Fu;
    unsigned int bits = (p & 0x80000000u) | ((e5 + 96u) << 23) |
                        (((p >> 17) & 0x1FFu) << 14);
    v = (e5 == 0u) ? 0.0f : __uint_as_float(bits);
}

__device__ __forceinline__ unsigned int pack_val(float val) {
    unsigned int b  = __float_as_uint(val);
    unsigned int rb = b + 0x1FFFu + ((b >> 14) & 1u);  // RNE to 9 mant
    int exp8 = (int)((rb >> 23) & 0xFF);
    unsigned int pk = 0u;
    if (exp8 > 96)                                     // else flush to 0
        pk = (b & 0x80000000u) | ((unsigned int)(exp8 - 96) << 26) |
             (((rb >> 14) & 0x1FFu) << 17);
    return pk;
}

// ---------------- CSR build + precompute ----------------

// dm[n] = d*mask^2 ; F_bf = bf16(F)
__global__ __launch_bounds__(BLK) void precompute_kernel(
    const float* __restrict__ F, const float* __restrict__ d,
    const float* __restrict__ mask, float* __restrict__ dm,
    unsigned short* __restrict__ F_bf) {
    int i = blockIdx.x * BLK + threadIdx.x;       // over NF/4
    if (i >= NF / 4) return;
    float4 f = ((const float4*)F)[i];
    ushort4 o;
    o.x = f2bf(f.x); o.y = f2bf(f.y); o.z = f2bf(f.z); o.w = f2bf(f.w);
    ((ushort4*)F_bf)[i] = o;
    if ((i & (FEAT_ / 4 - 1)) == 0) {
        int n = i / (FEAT_ / 4);
        dm[n] = d[n] * mask[n] * mask[n];
    }
}

// Fused histogram + bucket partition. Reads rows/cols/vals ONCE.
// (a) cnt8 histogram (NCPY privatized copies, blockIdx&7) for the scan;
// (b) packs pk inline; (c) partitions edge into bucket row/2500 via
// block-local LDS rank + one global atomicAdd(bcur[bkt], lcnt) per block;
// stage_pk/stage_rk16 written in per-bucket contiguous runs.
// NEDGE = 5000*256 exactly -> no bounds check.
__global__ __launch_bounds__(BLK) void hist_stage_kernel(
    const int* __restrict__ rows, const int* __restrict__ cols,
    const float* __restrict__ vals, int* __restrict__ cnt8,
    int* __restrict__ bcur, unsigned int* __restrict__ stage_pk,
    unsigned short* __restrict__ stage_rk) {
    __shared__ int lcnt[NXCD];
    __shared__ int lbase[NXCD];
    int e = blockIdx.x * BLK + threadIdx.x;
    if (threadIdx.x < NXCD) lcnt[threadIdx.x] = 0;
    __syncthreads();
    int row = rows[e];
    int col = cols[e];
    float val = vals[e];
    int k = e / NNZ_;
    int copy = blockIdx.x & (NCPY - 1);
    atomicAdd(&cnt8[copy * KN + row * K_ + k], 1);
    int bkt = row / NPB;
    int r_loc = atomicAdd(&lcnt[bkt], 1);
    unsigned int pk = pack_val(val) | ((unsigned int)k << 15) |
                      (unsigned int)col;
    unsigned short rk16 = (unsigned short)((row - bkt * NPB) * K_ + k); // <10000
    __syncthreads();
    if (threadIdx.x < NXCD)
        lbase[threadIdx.x] = atomicAdd(&bcur[threadIdx.x], lcnt[threadIdx.x]);
    __syncthreads();
    int pos = bkt * CAP + lbase[bkt] + r_loc;
    stage_pk[pos] = pk;
    stage_rk[pos] = rk16;
}

// block-local exclusive scan over summed copies + block sums
__global__ __launch_bounds__(256) void scan1_kernel(
    const int* __restrict__ cnt8, int* __restrict__ loc,
    int* __restrict__ bsum) {
    int i = blockIdx.x * 256 + threadIdx.x;
    int x = 0;
    if (i < KN) {
        #pragma unroll
        for (int c = 0; c < NCPY; ++c) x += cnt8[c * KN + i];
    }
    int lane = threadIdx.x & 63, wid = threadIdx.x >> 6;
    int v = x;
    #pragma unroll
    for (int off = 1; off < 64; off <<= 1) {
        int t = __shfl_up(v, off, 64);
        if (lane >= off) v += t;
    }
    __shared__ int ws[4];
    if (lane == 63) ws[wid] = v;
    __syncthreads();
    int add = 0;
    for (int u = 0; u < wid; ++u) add += ws[u];
    v += add;
    if (i < KN) loc[i] = v - x;
    if (threadIdx.x == 255) bsum[blockIdx.x] = v;
}

__global__ __launch_bounds__(512) void scan2_kernel(int* __restrict__ bsum) {
    int tid = threadIdx.x;
    int x = (tid < NSB) ? bsum[tid] : 0;
    int lane = tid & 63, wid = tid >> 6;
    int v = x;
    #pragma unroll
    for (int off = 1; off < 64; off <<= 1) {
        int t = __shfl_up(v, off, 64);
        if (lane >= off) v += t;
    }
    __shared__ int ws[8];
    if (lane == 63) ws[wid] = v;
    __syncthreads();
    int add = 0;
    for (int u = 0; u < wid; ++u) add += ws[u];
    v += add;
    if (tid < NSB) bsum[tid] = v - x;
}

__global__ __launch_bounds__(256) void scan3_kernel(
    const int* __restrict__ loc, const int* __restrict__ bsum,
    int* __restrict__ offs, int* __restrict__ cursor) {
    int i = blockIdx.x * 256 + threadIdx.x;
    if (i < KN) {
        int v = loc[i] + bsum[blockIdx.x];
        offs[i] = v;
        cursor[i] = v;
    }
    if (i == 0) offs[KN] = NEDGE;
}

// Pass 2: bucket = blockIdx%8 (round-robin block->XCD keeps cursor/cmeta
// lines XCD-local), chunk = blockIdx/8. Staged edges read contiguously
// ONCE; cursor atomic + cmeta scattered write within the bucket's range.
__global__ __launch_bounds__(BLK) void scatter2_kernel(
    const unsigned int* __restrict__ stage_pk,
    const unsigned short* __restrict__ stage_rk,
    const int* __restrict__ bcur, int* __restrict__ cursor,
    unsigned int* __restrict__ cmeta) {
    int bkt   = blockIdx.x & (NXCD - 1);
    int chunk = blockIdx.x >> 3;
    int cnt   = bcur[bkt];
    int base  = chunk * EPV + threadIdx.x;
    int rkb   = bkt * NPB * K_;
    #pragma unroll
    for (int i = 0; i < EPV / BLK; ++i) {
        int idx = base + i * BLK;
        if (idx >= cnt) continue;
        unsigned int pk = stage_pk[bkt * CAP + idx];
        int rk = rkb + (int)stage_rk[bkt * CAP + idx];
        int pos = atomicAdd(&cursor[rk], 1);
        cmeta[pos] = pk;
    }
}

// ---------------- iteration kernels ----------------

// Accumulate one <=64-edge chunk whose packed meta is ALREADY decoded into
// per-lane (c_l, v_l); lanes >= n hold (padc, 0). bf16 gather (ushort4),
// fp32 FMA, gathers batched BATCH-deep for memory-level parallelism.
template <int BATCH>
__device__ __forceinline__ void chunk_accum(
    int c_l, float v_l, int n, const ushort4* __restrict__ Xb,
    int sub, int q, float4& acc) {
    int iters = (n + 3) >> 2;
    int itersPad = (iters + BATCH - 1) & ~(BATCH - 1);  // <= 16
    for (int it0 = 0; it0 < itersPad; it0 += BATCH) {
        float   vv[BATCH];
        ushort4 xx[BATCH];
        #pragma unroll
        for (int u = 0; u < BATCH; ++u) {
            int j = 4 * (it0 + u) + sub;      // < 64
            int   c = __shfl(c_l, j, 64);
            vv[u]   = __shfl(v_l, j, 64);
            xx[u]   = Xb[c * (FEAT_ / 4) + q];
        }
        #pragma unroll
        for (int u = 0; u < BATCH; ++u) {
            acc.x += vv[u] * bf2f(xx[u].x);
            acc.y += vv[u] * bf2f(xx[u].y);
            acc.z += vv[u] * bf2f(xx[u].z);
            acc.w += vv[u] * bf2f(xx[u].w);
        }
    }
}

// Fallback (not pipelined): load+decode+accumulate windows [beg,end).
// Only runs for rare overflow chunks beyond the prefetched ones.
template <int BATCH>
__device__ __forceinline__ void tail_accum(
    const unsigned int* __restrict__ cmeta, const ushort4* __restrict__ Xb,
    int beg, int end, int lane, int sub, int q, int padc, float4& acc) {
    for (int eb = beg; eb < end; eb += 64) {
        int n = end - eb;
        if (n > 64) n = 64;
        int   c_l = padc;
        float v_l = 0.0f;
        if (lane < n) {
            unsigned int p = cmeta[eb + lane];
            decode_meta(p, c_l, v_l);
        }
        chunk_accum<BATCH>(c_l, v_l, n, Xb, sub, q, acc);
    }
}

__device__ __forceinline__ void butterfly4(float4& a) {
    #pragma unroll
    for (int m = 16; m <= 32; m <<= 1) {
        a.x += __shfl_xor(a.x, m, 64);
        a.y += __shfl_xor(a.y, m, 64);
        a.z += __shfl_xor(a.z, m, 64);
        a.w += __shfl_xor(a.w, m, 64);
    }
}

// wave per R_SP contiguous CSR rows (rowid = n*K+k); acc = (W_k @ X)[n];
// fused v-update into bf16 V_bf (layout [k][n]). FIRST: Y=0, X=F_bf.
// Meta for row r+1 prefetched during row r (R2 pipeline).
template <bool FIRST>
__global__ __launch_bounds__(BLK) void spmm_fused_kernel(
    const int* __restrict__ offs, const unsigned int* __restrict__ cmeta,
    const unsigned short* __restrict__ Xb,
    const float* __restrict__ d, unsigned short* __restrict__ V_bf) {
    int wave = (blockIdx.x * BLK + threadIdx.x) >> 6;
    int lane = threadIdx.x & 63;
    int sub  = lane >> 4, q = lane & 15;
    int base = wave * R_SP;
    if (base >= KN) return;
    int off_l = 0;
    if (lane <= R_SP) {
        int i = base + lane;
        if (i > KN) i = KN;
        off_l = offs[i];
    }
    const ushort4* X4 = (const ushort4*)Xb;
    ushort4* V4 = (ushort4*)V_bf;

    // prefetch row 0 meta (first chunk)
    unsigned int p_cur = 0u;
    {
        int b0 = __shfl(off_l, 0, 64), e0 = __shfl(off_l, 1, 64);
        int nn = e0 - b0;
        if (nn > 64) nn = 64;
        if (lane < nn) p_cur = cmeta[b0 + lane];
    }
    for (int r = 0; r < R_SP; ++r) {
        int w = base + r;                // rowid = n*K + k
        if (w >= KN) break;
        int k = w & (K_ - 1);
        int n = w >> 2;
        int beg = __shfl(off_l, r, 64);
        int end = __shfl(off_l, r + 1, 64);
        // issue next row's meta load (overlaps this row's gathers)
        unsigned int p_nxt = 0u;
        if (r + 1 < R_SP && w + 1 < KN) {
            int bn = __shfl(off_l, r + 1, 64), en = __shfl(off_l, r + 2, 64);
            int nn = en - bn;
            if (nn > 64) nn = 64;
            if (lane < nn) p_nxt = cmeta[bn + lane];
        }
        // decode current row's prefetched meta
        int n_e = end - beg;
        if (n_e > 64) n_e = 64;
        int   c_l = k * N_;              // pad col (valid after base adjust)
        float v_l = 0.0f;
        if (lane < n_e) decode_meta(p_cur, c_l, v_l);
        // decoded col' = k*N + col; recover shared-X indexing by base adjust
        const ushort4* X4m = X4 - (size_t)k * N_ * (FEAT_ / 4);
        float4 acc = {0.f, 0.f, 0.f, 0.f};
        chunk_accum<4>(c_l, v_l, n_e, X4m, sub, q, acc);
        if (end - beg > 64)              // astronomically rare
            tail_accum<4>(cmeta, X4m, beg + 64, end, lane, sub, q, k * N_, acc);
        p_cur = p_nxt;
        butterfly4(acc);                 // all lanes hold row sums
        if (sub == 0) {
            int idx4 = (k * N_ + n) * (FEAT_ / 4) + q;
            float thr = c_nu[k] * d[n];
            float4 y;
            if (FIRST) {
                y = make_float4(0.f, 0.f, 0.f, 0.f);
            } else {
                ushort4 vp = V4[idx4];   // v_{t-1}
                y.x = acc.x + bf2f(vp.x); y.y = acc.y + bf2f(vp.y);
                y.z = acc.z + bf2f(vp.z); y.w = acc.w + bf2f(vp.w);
            }
            ushort4 o;
            o.x = f2bf(y.x - softf(acc.x + y.x, thr));
            o.y = f2bf(y.y - softf(acc.y + y.y, thr));
            o.z = f2bf(y.z - softf(acc.z + y.z, thr));
            o.w = f2bf(y.w - softf(acc.w + y.w, thr));
            V4[idx4] = o;                // v_t
        }
    }
}

// wave per R_WT nodes: node n's edges over ALL k are one flat contiguous
// segment [offs[4n], offs[4n+4]) gathering V_bf[col'] directly.
// Segments are mean 64 +- 8 edges -> prefetch TWO 64-edge meta chunks for
// node r+1 during node r; chunks beyond 128 via tail_accum (negligible).
// U = (dm*F - acc)/(dm+1); fp32 U stored ONLY when LAST (d_out graded
// once); bf16 copy always (it feeds the next spmm's gathers).
template <bool LAST>
__global__ __launch_bounds__(BLK) void wtv_u_kernel(
    const int* __restrict__ offs, const unsigned int* __restrict__ cmeta,
    const unsigned short* __restrict__ V_bf,
    const float* __restrict__ F, const float* __restrict__ dm,
    float* __restrict__ U, unsigned short* __restrict__ U_bf) {
    int wave = (blockIdx.x * BLK + threadIdx.x) >> 6;
    int lane = threadIdx.x & 63;
    int sub  = lane >> 4, q = lane & 15;
    int base = wave * R_WT;
    if (base >= N_) return;
    int off_l = 0;
    if (lane <= K_ * R_WT) {             // 17 offsets
        int i = K_ * base + lane;
        if (i > KN) i = KN;
        off_l = offs[i];
    }
    const ushort4* V4 = (const ushort4*)V_bf;

    // prefetch node 0 meta (two chunks)
    unsigned int p0 = 0u, p1 = 0u;
    {
        int b0 = __shfl(off_l, 0, 64), e0 = __shfl(off_l, K_, 64);
        int nn = e0 - b0;
        if (lane < nn) p0 = cmeta[b0 + lane];
        if (64 + lane < nn) p1 = cmeta[b0 + 64 + lane];
    }
    for (int r = 0; r < R_WT; ++r) {
        int n = base + r;
        if (n >= N_) break;
        int beg = __shfl(off_l, K_ * r, 64);
        int end = __shfl(off_l, K_ * r + K_, 64);
        // issue next node's meta loads (overlap this node's gathers)
        unsigned int q0 = 0u, q1 = 0u;
        if (r + 1 < R_WT && n + 1 < N_) {
            int bn = __shfl(off_l, K_ * r + K_, 64);
            int en = __shfl(off_l, K_ * r + 2 * K_, 64);
            int nn = en - bn;
            if (lane < nn) q0 = cmeta[bn + lane];
            if (64 + lane < nn) q1 = cmeta[bn + 64 + lane];
        }
        int ne = end - beg;
        float4 acc = {0.f, 0.f, 0.f, 0.f};
        // chunk 0
        {
            int n0 = ne > 64 ? 64 : ne;
            int   c_l = 0;
            float v_l = 0.0f;
            if (lane < n0) decode_meta(p0, c_l, v_l);
            chunk_accum<8>(c_l, v_l, n0, V4, sub, q, acc);
        }
        // chunk 1
        if (ne > 64) {
            int n1 = ne - 64;
            if (n1 > 64) n1 = 64;
            int   c_l = 0;
            float v_l = 0.0f;
            if (lane < n1) decode_meta(p1, c_l, v_l);
            chunk_accum<2>(c_l, v_l, n1, V4, sub, q, acc);
        }
        if (ne > 128)                     // negligible tail
            tail_accum<2>(cmeta, V4, beg + 128, end, lane, sub, q, 0, acc);
        p0 = q0; p1 = q1;
        butterfly4(acc);
        if (sub == 0) {
            int idx4 = n * (FEAT_ / 4) + q;
            float dmv = dm[n];
            float r2 = 1.0f / (dmv + 1.0f);
            float4 f = ((const float4*)F)[idx4];
            float4 o;
            o.x = (dmv * f.x - acc.x) * r2; o.y = (dmv * f.y - acc.y) * r2;
            o.z = (dmv * f.z - acc.z) * r2; o.w = (dmv * f.w - acc.w) * r2;
            if (LAST) ((float4*)U)[idx4] = o;
            ushort4 ob;
            ob.x = f2bf(o.x); ob.y = f2bf(o.y);
            ob.z = f2bf(o.z); ob.w = f2bf(o.w);
            ((ushort4*)U_bf)[idx4] = ob;
        }
    }
}

extern "C" void kernel_launch(void* const* d_in, const int* in_sizes, int n_in,
                              void* d_out, int out_size, void* d_ws, size_t ws_size,
                              hipStream_t stream) {
    const float* F      = (const float*)d_in[0];
    const int*   w_rows = (const int*)d_in[1];
    const int*   w_cols = (const int*)d_in[2];
    const float* w_vals = (const float*)d_in[3];
    const float* d      = (const float*)d_in[4];
    const float* mask   = (const float*)d_in[5];
    float* U = (float*)d_out;

    // workspace layout (~24 MB persistent; staging aliases V_bf)
    unsigned int* cmeta  = (unsigned int*)d_ws;               // NEDGE u32
    unsigned short* V_bf = (unsigned short*)(cmeta + NEDGE);  // KN*FEAT us
    unsigned short* U_bf = V_bf + (size_t)KN * FEAT_;         // NF us
    unsigned short* F_bf = U_bf + NF;                         // NF us
    float* dm     = (float*)(F_bf + NF);                      // N
    int*   cnt8   = (int*)(dm + N_);                          // NCPY*KN
    int*   bcur   = cnt8 + NCPY * KN;                         // NXCD (8)
    int*   loc    = bcur + NXCD;                              // KN
    int*   bsum   = loc + KN;                                 // pad 512
    int*   offs   = bsum + 512;                               // KN+1
    int*   cursor = offs + KN + 1;                            // KN
    // staging: dead after scatter2, before first spmm writes V_bf.
    // 8*CAP*4 + 8*CAP*2 = 7.96 MB <= sizeof(V_bf) = 10.24 MB.
    unsigned int*   stage_pk = (unsigned int*)V_bf;           // NXCD*CAP u32
    unsigned short* stage_rk = (unsigned short*)(stage_pk + NXCD * CAP);

    const int gEdge = NEDGE / BLK;                // 5000
    const int gNF4  = (NF / 4) / BLK;             // 1250

    // ---- CSR build + precompute ----
    hipMemsetAsync(cnt8, 0, ((size_t)NCPY * KN + NXCD) * 4, stream);
    precompute_kernel<<<gNF4, BLK, 0, stream>>>(F, d, mask, dm, F_bf);
    hist_stage_kernel<<<gEdge, BLK, 0, stream>>>(w_rows, w_cols, w_vals,
                                                 cnt8, bcur, stage_pk, stage_rk);
    scan1_kernel<<<NSB, 256, 0, stream>>>(cnt8, loc, bsum);
    scan2_kernel<<<1, 512, 0, stream>>>(bsum);
    scan3_kernel<<<NSB, 256, 0, stream>>>(loc, bsum, offs, cursor);
    scatter2_kernel<<<NCH * NXCD, BLK, 0, stream>>>(stage_pk, stage_rk,
                                                    bcur, cursor, cmeta);

    // ---- iterations ----
    spmm_fused_kernel<true><<<NB_SP, BLK, 0, stream>>>(offs, cmeta, F_bf, d, V_bf);
    for (int it = 0; it < NITER; ++it) {
        if (it < NITER - 1) {
            wtv_u_kernel<false><<<NB_WT, BLK, 0, stream>>>(offs, cmeta, V_bf,
                                                           F, dm, U, U_bf);
            spmm_fused_kernel<false><<<NB_SP, BLK, 0, stream>>>(offs, cmeta,
                                                                U_bf, d, V_bf);
        } else {
            wtv_u_kernel<true><<<NB_WT, BLK, 0, stream>>>(offs, cmeta, V_bf,
                                                          F, dm, U, U_bf);
        }
    }
}

// Round 8
// 817.475 us; speedup vs baseline: 1.1302x; 1.1302x over previous
//
#include <hip/hip_runtime.h>

// NodeDenoisingADMM: N=20000, FEAT=64, K=4, NNZ=320000, NU=2.0, GAMMA=1.0, J=3
// 14 scan iterations, output = final U (N,FEAT) fp32.
//
// State reduction (GAMMA=1): carried state is v alone.
//   S_t = W_k @ U_t ; Y_t = S_t + v_{t-1} ; Z_t = soft(S_t + Y_t, nu_k d)
//   v_t = Y_t - Z_t ; U_{t+1} = (dm*F - sum_k W_k v_k)/(dm+1), dm = d*mask^2
//
// Node-major CSR: rowid = n*K + k. Edge meta packed in 4 B:
//   [31] sign | [30:26] exp5 (bias 96, 0 => value 0) | [25:17] mant9 (RNE)
//   | [16:15] k | [14:0] col       (rel err 2^-11 < bf16 operand err)
// Scatter is XCD-FILTERED (8 buckets by row/2500, block handles bucket
// blockIdx%8) so cursor/cmeta dirty lines live in ONE XCD's L2.
//
// HISTORY: R1 k-phase wtv: REGRESS. R2 meta pipeline: WIN (keep).
// R3 NT loads: REGRESS. R4/R5 deep gather pipeline: REGRESS (+80 VGPR
// occupancy cliff; TLP > ILP). R6 scatter atomic-MLP: REGRESS (+12us).
// R7 two-pass bucket scatter: REGRESS (write-amplified rank-scatter,
// LDS-atomic serialization). CSR build is now FROZEN at the R2 form.
// KEPT: LAST-only fp32 U store.
// R8: spmm SUB-OWNS-ROW restructure. Tile = node n = 4 consecutive CSR
// rows (k=0..3); sub = lane>>4 = k. Cooperative meta load of the node's
// flat span (1-3 VMEM vs 4) -> decode once per lane (/4) -> skewed LDS
// table of (col*16, v) -> each sub walks its OWN row via 1 ds_read_b64
// per step (16 lanes/sub read same slot = broadcast, conflict-free).
// Eliminates ALL broadcast bpermutes AND the butterfly (each sub owns its
// row sum); V load/store become wave-wide (/4 VMEM). LDS ops per 4 rows:
// ~72 -> ~28. Meta prefetched one tile ahead (R2 pipeline, 3 VGPR only).
// wtv left at proven R2 form (isolation; port next round if spmm wins).

constexpr int N_    = 20000;
constexpr int FEAT_ = 64;
constexpr int K_    = 4;
constexpr int NNZ_  = 320000;
constexpr int NF    = N_ * FEAT_;     // 1,280,000
constexpr int KN    = K_ * N_;        // 80,000 CSR rows
constexpr int NEDGE = K_ * NNZ_;      // 1,280,000
constexpr int NITER = 14;
constexpr int BLK   = 256;
constexpr int NSB   = (KN + 255) / 256;  // 313 scan blocks
constexpr int NCPY  = 8;                 // hist privatization copies
constexpr int NXCD  = 8;
constexpr int EPV   = 2048;              // edges per scatter block
constexpr int NVB   = NEDGE / EPV;       // 625 virtual blocks

// spmm4: 3 nodes (tiles) per wave -> 12 CSR rows/wave
constexpr int T_SP  = 3;
constexpr int NW_SP = (N_ + T_SP - 1) / T_SP;             // 6667 waves
constexpr int NB_SP4 = (NW_SP + 3) / 4;                   // 1667 blocks
constexpr int TABSZ = 204;               // 192 slots + skew pad

constexpr int R_WT  = 4;                           // nodes/wave, wtv
constexpr int NB_WT = ((N_ + R_WT - 1) / R_WT + 3) / 4;   // 1250 blocks

__constant__ float c_nu[4] = {0.0f, 2.0f, 0.5f, 0.125f};

__device__ __forceinline__ float softf(float x, float t) {
    float a = fabsf(x) - t;
    a = a > 0.0f ? a : 0.0f;
    return copysignf(a, x);
}

__device__ __forceinline__ float bf2f(unsigned short u) {
    union { unsigned int i; float f; } x;
    x.i = ((unsigned int)u) << 16;
    return x.f;
}
__device__ __forceinline__ unsigned short f2bf(float f) {   // RNE
    union { float f; unsigned int i; } x;
    x.f = f;
    unsigned int r = x.i + 0x7FFFu + ((x.i >> 16) & 1u);
    return (unsigned short)(r >> 16);
}

__device__ __forceinline__ void decode_meta(unsigned int p, int& c, float& v) {
    c = (int)((p >> 15) & 3u) * N_ + (int)(p & 0x7FFFu);
    unsigned int e5 = (p >> 26) & 0x1Fu;
    unsigned int bits = (p & 0x80000000u) | ((e5 + 96u) << 23) |
                        (((p >> 17) & 0x1FFu) << 14);
    v = (e5 == 0u) ? 0.0f : __uint_as_float(bits);
}

// table entry: low32 = col*16 (ushort4 index base), high32 = fp32 val bits
__device__ __forceinline__ unsigned long long enc_tab(unsigned int p) {
    unsigned int c16 = (p & 0x7FFFu) << 4;
    unsigned int e5 = (p >> 26) & 0x1Fu;
    unsigned int vb = (p & 0x80000000u) | ((e5 + 96u) << 23) |
                      (((p >> 17) & 0x1FFu) << 14);
    vb = (e5 == 0u) ? 0u : vb;
    return ((unsigned long long)vb << 32) | (unsigned long long)c16;
}

__device__ __forceinline__ void fma4(float4& acc, float v, const ushort4& x) {
    acc.x += v * bf2f(x.x);
    acc.y += v * bf2f(x.y);
    acc.z += v * bf2f(x.z);
    acc.w += v * bf2f(x.w);
}

// ---------------- CSR build + precompute ----------------

// dm[n] = d*mask^2 ; F_bf = bf16(F)
__global__ __launch_bounds__(BLK) void precompute_kernel(
    const float* __restrict__ F, const float* __restrict__ d,
    const float* __restrict__ mask, float* __restrict__ dm,
    unsigned short* __restrict__ F_bf) {
    int i = blockIdx.x * BLK + threadIdx.x;       // over NF/4
    if (i >= NF / 4) return;
    float4 f = ((const float4*)F)[i];
    ushort4 o;
    o.x = f2bf(f.x); o.y = f2bf(f.y); o.z = f2bf(f.z); o.w = f2bf(f.w);
    ((ushort4*)F_bf)[i] = o;
    if ((i & (FEAT_ / 4 - 1)) == 0) {
        int n = i / (FEAT_ / 4);
        dm[n] = d[n] * mask[n] * mask[n];
    }
}

// rowid = rows[e]*K + k ; privatized copies (blockIdx&7)
__global__ __launch_bounds__(BLK) void hist_kernel(
    const int* __restrict__ rows, int* __restrict__ cnt8) {
    int e = blockIdx.x * BLK + threadIdx.x;
    if (e >= NEDGE) return;
    int k = e / NNZ_;
    int copy = blockIdx.x & (NCPY - 1);
    atomicAdd(&cnt8[copy * KN + rows[e] * K_ + k], 1);
}

// block-local exclusive scan over summed copies + block sums
__global__ __launch_bounds__(256) void scan1_kernel(
    const int* __restrict__ cnt8, int* __restrict__ loc,
    int* __restrict__ bsum) {
    int i = blockIdx.x * 256 + threadIdx.x;
    int x = 0;
    if (i < KN) {
        #pragma unroll
        for (int c = 0; c < NCPY; ++c) x += cnt8[c * KN + i];
    }
    int lane = threadIdx.x & 63, wid = threadIdx.x >> 6;
    int v = x;
    #pragma unroll
    for (int off = 1; off < 64; off <<= 1) {
        int t = __shfl_up(v, off, 64);
        if (lane >= off) v += t;
    }
    __shared__ int ws[4];
    if (lane == 63) ws[wid] = v;
    __syncthreads();
    int add = 0;
    for (int u = 0; u < wid; ++u) add += ws[u];
    v += add;
    if (i < KN) loc[i] = v - x;
    if (threadIdx.x == 255) bsum[blockIdx.x] = v;
}

__global__ __launch_bounds__(512) void scan2_kernel(int* __restrict__ bsum) {
    int tid = threadIdx.x;
    int x = (tid < NSB) ? bsum[tid] : 0;
    int lane = tid & 63, wid = tid >> 6;
    int v = x;
    #pragma unroll
    for (int off = 1; off < 64; off <<= 1) {
        int t = __shfl_up(v, off, 64);
        if (lane >= off) v += t;
    }
    __shared__ int ws[8];
    if (lane == 63) ws[wid] = v;
    __syncthreads();
    int add = 0;
    for (int u = 0; u < wid; ++u) add += ws[u];
    v += add;
    if (tid < NSB) bsum[tid] = v - x;
}

__global__ __launch_bounds__(256) void scan3_kernel(
    const int* __restrict__ loc, const int* __restrict__ bsum,
    int* __restrict__ offs, int* __restrict__ cursor) {
    int i = blockIdx.x * 256 + threadIdx.x;
    if (i < KN) {
        int v = loc[i] + bsum[blockIdx.x];
        offs[i] = v;
        cursor[i] = v;
    }
    if (i == 0) offs[KN] = NEDGE;
}

// XCD-filtered scatter (R2 form — frozen; R3/R6/R7 variants all regressed).
__global__ __launch_bounds__(BLK) void scatter_kernel(
    const int* __restrict__ rows, const int* __restrict__ cols,
    const float* __restrict__ vals, int* __restrict__ cursor,
    unsigned int* __restrict__ cmeta) {
    int xcd = blockIdx.x & (NXCD - 1);
    int vb  = blockIdx.x >> 3;
    int ebase = vb * EPV;
    #pragma unroll
    for (int i = 0; i < EPV / BLK; ++i) {
        int e = ebase + i * BLK + threadIdx.x;
        int row = rows[e];
        if (row / (N_ / NXCD) != xcd) continue;
        int k = e / NNZ_;
        unsigned int b  = __float_as_uint(vals[e]);
        unsigned int rb = b + 0x1FFFu + ((b >> 14) & 1u);  // RNE to 9 mant
        int exp8 = (int)((rb >> 23) & 0xFF);
        unsigned int pk = 0u;
        if (exp8 > 96)                                     // else flush to 0
            pk = (b & 0x80000000u) | ((unsigned int)(exp8 - 96) << 26) |
                 (((rb >> 14) & 0x1FFu) << 17);
        pk |= ((unsigned int)k << 15) | (unsigned int)cols[e];
        int pos = atomicAdd(&cursor[row * K_ + k], 1);
        cmeta[pos] = pk;
    }
}

// ---------------- iteration kernels ----------------

// (chunk_accum/tail_accum/butterfly4 retained for wtv's R2 structure)
template <int BATCH>
__device__ __forceinline__ void chunk_accum(
    int c_l, float v_l, int n, const ushort4* __restrict__ Xb,
    int sub, int q, float4& acc) {
    int iters = (n + 3) >> 2;
    int itersPad = (iters + BATCH - 1) & ~(BATCH - 1);  // <= 16
    for (int it0 = 0; it0 < itersPad; it0 += BATCH) {
        float   vv[BATCH];
        ushort4 xx[BATCH];
        #pragma unroll
        for (int u = 0; u < BATCH; ++u) {
            int j = 4 * (it0 + u) + sub;      // < 64
            int   c = __shfl(c_l, j, 64);
            vv[u]   = __shfl(v_l, j, 64);
            xx[u]   = Xb[c * (FEAT_ / 4) + q];
        }
        #pragma unroll
        for (int u = 0; u < BATCH; ++u) {
            acc.x += vv[u] * bf2f(xx[u].x);
            acc.y += vv[u] * bf2f(xx[u].y);
            acc.z += vv[u] * bf2f(xx[u].z);
            acc.w += vv[u] * bf2f(xx[u].w);
        }
    }
}

template <int BATCH>
__device__ __forceinline__ void tail_accum(
    const unsigned int* __restrict__ cmeta, const ushort4* __restrict__ Xb,
    int beg, int end, int lane, int sub, int q, int padc, float4& acc) {
    for (int eb = beg; eb < end; eb += 64) {
        int n = end - eb;
        if (n > 64) n = 64;
        int   c_l = padc;
        float v_l = 0.0f;
        if (lane < n) {
            unsigned int p = cmeta[eb + lane];
            decode_meta(p, c_l, v_l);
        }
        chunk_accum<BATCH>(c_l, v_l, n, Xb, sub, q, acc);
    }
}

__device__ __forceinline__ void butterfly4(float4& a) {
    #pragma unroll
    for (int m = 16; m <= 32; m <<= 1) {
        a.x += __shfl_xor(a.x, m, 64);
        a.y += __shfl_xor(a.y, m, 64);
        a.z += __shfl_xor(a.z, m, 64);
        a.w += __shfl_xor(a.w, m, 64);
    }
}

// spmm4: wave handles T_SP=3 node-tiles; tile = node n = CSR rows
// n*4+k, k=0..3; sub (lane>>4) == k. Per tile: cooperative meta load of
// the flat span [offs[4n], offs[4n+4]) (1-3 chunks), decode once/lane,
// deposit (col*16, v) into skewed LDS table, then each sub serially walks
// its own row: 1 ds_read_b64 per step (broadcast within sub), gather,
// fma. No bpermute broadcast, no butterfly; epilogue is wave-wide.
// Meta for tile t+1 prefetched (raw u32 regs) before tile t's steps.
// Span >192 overflow handled by a uniform serial loop (never in practice).
template <bool FIRST>
__global__ __launch_bounds__(BLK) void spmm_fused_kernel(
    const int* __restrict__ offs, const unsigned int* __restrict__ cmeta,
    const unsigned short* __restrict__ Xb,
    const float* __restrict__ d, unsigned short* __restrict__ V_bf) {
    __shared__ unsigned long long tab[4][2][TABSZ];
    int wave = (blockIdx.x * BLK + threadIdx.x) >> 6;
    int lane = threadIdx.x & 63;
    int sub  = lane >> 4, q = lane & 15;
    int widx = threadIdx.x >> 6;
    int n0 = wave * T_SP;
    if (n0 >= N_) return;
    int off_l = 0;
    if (lane <= 4 * T_SP) {              // 13 offsets
        int i = n0 * K_ + lane;
        if (i > KN) i = KN;
        off_l = offs[i];
    }
    const ushort4* X4 = (const ushort4*)Xb;
    ushort4* V4 = (ushort4*)V_bf;
    float nu_s = sub == 0 ? 0.0f : (sub == 1 ? 2.0f : (sub == 2 ? 0.5f : 0.125f));

    // prologue: tile 0 span + raw meta
    int tb = __shfl(off_l, 0, 64);
    int te = __shfl(off_l, 4, 64);
    int span = te - tb;
    unsigned int pA = 0, pB = 0, pC = 0;
    if (lane < span)       pA = cmeta[tb + lane];
    if (64 + lane < span)  pB = cmeta[tb + 64 + lane];
    if (128 + lane < span) pC = cmeta[tb + 128 + lane];

    #pragma unroll
    for (int t = 0; t < T_SP; ++t) {
        int n = n0 + t;
        if (n >= N_) break;
        unsigned long long* Tc = tab[widx][t & 1];
        // per-sub window within the span
        int bs = __shfl(off_l, 4 * t + sub, 64);
        int es = __shfl(off_l, 4 * t + sub + 1, 64);
        int pre = bs - tb;
        int cnt = es - bs;
        int jmax = 192 - pre;
        jmax = cnt < jmax ? cnt : jmax;
        if (jmax < 0) jmax = 0;
        int maxc = jmax;
        { int o1 = __shfl_xor(maxc, 16, 64); maxc = maxc > o1 ? maxc : o1;
          int o2 = __shfl_xor(maxc, 32, 64); maxc = maxc > o2 ? maxc : o2; }
        // decode prefetched meta -> skewed LDS table
        if (lane < span)       { int s = lane;       Tc[s + (s >> 4)] = enc_tab(pA); }
        if (64 + lane < span)  { int s = 64 + lane;  Tc[s + (s >> 4)] = enc_tab(pB); }
        if (128 + lane < span) { int s = 128 + lane; Tc[s + (s >> 4)] = enc_tab(pC); }
        // prefetch next tile's raw meta (flies over this tile's steps)
        int tbn = te, ten = te, spann = 0;
        unsigned int nA = 0, nB = 0, nC = 0;
        if (t + 1 < T_SP && n + 1 < N_) {
            ten = __shfl(off_l, 4 * t + 8, 64);
            spann = ten - tbn;
            if (lane < spann)       nA = cmeta[tbn + lane];
            if (64 + lane < spann)  nB = cmeta[tbn + 64 + lane];
            if (128 + lane < spann) nC = cmeta[tbn + 128 + lane];
        }
        // table writes visible before reads (same wave; explicit drain)
        asm volatile("s_waitcnt lgkmcnt(0)" ::: "memory");
        // steps: each sub walks its own row, 4-deep gather batches
        float4 acc = {0.f, 0.f, 0.f, 0.f};
        for (int i0 = 0; i0 < maxc; i0 += 4) {
            float vv[4]; int cc[4];
            #pragma unroll
            for (int u = 0; u < 4; ++u) {
                int j = i0 + u;
                bool ok = j < jmax;
                int slot = ok ? pre + j : 0;
                unsigned long long e = Tc[slot + (slot >> 4)];
                cc[u] = (int)(unsigned int)e;
                vv[u] = ok ? __uint_as_float((unsigned int)(e >> 32)) : 0.0f;
            }
            ushort4 xx[4];
            #pragma unroll
            for (int u = 0; u < 4; ++u) xx[u] = X4[cc[u] + q];
            #pragma unroll
            for (int u = 0; u < 4; ++u) fma4(acc, vv[u], xx[u]);
        }
        // span >192 overflow: uniform serial walk (never in practice)
        if (span > 192) {
            for (int e = tb + 192; e < te; ++e) {
                unsigned int p = cmeta[e];
                int ke = (int)((p >> 15) & 3u);
                unsigned long long en = enc_tab(p);
                if (sub == ke) {
                    ushort4 x = X4[(int)(unsigned int)en + q];
                    fma4(acc, __uint_as_float((unsigned int)(en >> 32)), x);
                }
            }
        }
        // epilogue: wave-wide (each lane owns 4 feats of row (n, k=sub))
        {
            float dn = d[n];
            int idx4 = (sub * N_ + n) * (FEAT_ / 4) + q;
            float thr = nu_s * dn;
            float4 y;
            if (FIRST) {
                y = make_float4(0.f, 0.f, 0.f, 0.f);
            } else {
                ushort4 vp = V4[idx4];
                y.x = acc.x + bf2f(vp.x); y.y = acc.y + bf2f(vp.y);
                y.z = acc.z + bf2f(vp.z); y.w = acc.w + bf2f(vp.w);
            }
            ushort4 o;
            o.x = f2bf(y.x - softf(acc.x + y.x, thr));
            o.y = f2bf(y.y - softf(acc.y + y.y, thr));
            o.z = f2bf(y.z - softf(acc.z + y.z, thr));
            o.w = f2bf(y.w - softf(acc.w + y.w, thr));
            V4[idx4] = o;
        }
        // rotate pipeline state
        tb = tbn; te = ten; span = spann;
        pA = nA; pB = nB; pC = nC;
    }
}

// wtv: proven R2 structure (meta pipeline, butterfly reduce), LAST store.
template <bool LAST>
__global__ __launch_bounds__(BLK) void wtv_u_kernel(
    const int* __restrict__ offs, const unsigned int* __restrict__ cmeta,
    const unsigned short* __restrict__ V_bf,
    const float* __restrict__ F, const float* __restrict__ dm,
    float* __restrict__ U, unsigned short* __restrict__ U_bf) {
    int wave = (blockIdx.x * BLK + threadIdx.x) >> 6;
    int lane = threadIdx.x & 63;
    int sub  = lane >> 4, q = lane & 15;
    int base = wave * R_WT;
    if (base >= N_) return;
    int off_l = 0;
    if (lane <= K_ * R_WT) {             // 17 offsets
        int i = K_ * base + lane;
        if (i > KN) i = KN;
        off_l = offs[i];
    }
    const ushort4* V4 = (const ushort4*)V_bf;

    unsigned int p0 = 0u, p1 = 0u;
    {
        int b0 = __shfl(off_l, 0, 64), e0 = __shfl(off_l, K_, 64);
        int nn = e0 - b0;
        if (lane < nn) p0 = cmeta[b0 + lane];
        if (64 + lane < nn) p1 = cmeta[b0 + 64 + lane];
    }
    for (int r = 0; r < R_WT; ++r) {
        int n = base + r;
        if (n >= N_) break;
        int beg = __shfl(off_l, K_ * r, 64);
        int end = __shfl(off_l, K_ * r + K_, 64);
        unsigned int q0 = 0u, q1 = 0u;
        if (r + 1 < R_WT && n + 1 < N_) {
            int bn = __shfl(off_l, K_ * r + K_, 64);
            int en = __shfl(off_l, K_ * r + 2 * K_, 64);
            int nn = en - bn;
            if (lane < nn) q0 = cmeta[bn + lane];
            if (64 + lane < nn) q1 = cmeta[bn + 64 + lane];
        }
        int ne = end - beg;
        float4 acc = {0.f, 0.f, 0.f, 0.f};
        {
            int n0c = ne > 64 ? 64 : ne;
            int   c_l = 0;
            float v_l = 0.0f;
            if (lane < n0c) decode_meta(p0, c_l, v_l);
            chunk_accum<8>(c_l, v_l, n0c, V4, sub, q, acc);
        }
        if (ne > 64) {
            int n1 = ne - 64;
            if (n1 > 64) n1 = 64;
            int   c_l = 0;
            float v_l = 0.0f;
            if (lane < n1) decode_meta(p1, c_l, v_l);
            chunk_accum<2>(c_l, v_l, n1, V4, sub, q, acc);
        }
        if (ne > 128)
            tail_accum<2>(cmeta, V4, beg + 128, end, lane, sub, q, 0, acc);
        p0 = q0; p1 = q1;
        butterfly4(acc);
        if (sub == 0) {
            int idx4 = n * (FEAT_ / 4) + q;
            float dmv = dm[n];
            float r2 = 1.0f / (dmv + 1.0f);
            float4 f = ((const float4*)F)[idx4];
            float4 o;
            o.x = (dmv * f.x - acc.x) * r2; o.y = (dmv * f.y - acc.y) * r2;
            o.z = (dmv * f.z - acc.z) * r2; o.w = (dmv * f.w - acc.w) * r2;
            if (LAST) ((float4*)U)[idx4] = o;
            ushort4 ob;
            ob.x = f2bf(o.x); ob.y = f2bf(o.y);
            ob.z = f2bf(o.z); ob.w = f2bf(o.w);
            ((ushort4*)U_bf)[idx4] = ob;
        }
    }
}

extern "C" void kernel_launch(void* const* d_in, const int* in_sizes, int n_in,
                              void* d_out, int out_size, void* d_ws, size_t ws_size,
                              hipStream_t stream) {
    const float* F      = (const float*)d_in[0];
    const int*   w_rows = (const int*)d_in[1];
    const int*   w_cols = (const int*)d_in[2];
    const float* w_vals = (const float*)d_in[3];
    const float* d      = (const float*)d_in[4];
    const float* mask   = (const float*)d_in[5];
    float* U = (float*)d_out;

    // workspace layout (~29 MB)
    unsigned int* cmeta  = (unsigned int*)d_ws;               // NEDGE u32
    unsigned short* V_bf = (unsigned short*)(cmeta + NEDGE);  // KN*FEAT us
    unsigned short* U_bf = V_bf + (size_t)KN * FEAT_;         // NF us
    unsigned short* F_bf = U_bf + NF;                         // NF us
    float* dm     = (float*)(F_bf + NF);                      // N
    int*   cnt8   = (int*)(dm + N_);                          // NCPY*KN
    int*   loc    = cnt8 + NCPY * KN;                         // KN
    int*   bsum   = loc + KN;                                 // pad 512
    int*   offs   = bsum + 512;                               // KN+1
    int*   cursor = offs + KN + 1;                            // KN

    const int gEdge = NEDGE / BLK;                // 5000
    const int gNF4  = (NF / 4) / BLK;             // 1250

    // ---- CSR build + precompute ----
    hipMemsetAsync(cnt8, 0, (size_t)NCPY * KN * 4, stream);
    precompute_kernel<<<gNF4, BLK, 0, stream>>>(F, d, mask, dm, F_bf);
    hist_kernel<<<gEdge, BLK, 0, stream>>>(w_rows, cnt8);
    scan1_kernel<<<NSB, 256, 0, stream>>>(cnt8, loc, bsum);
    scan2_kernel<<<1, 512, 0, stream>>>(bsum);
    scan3_kernel<<<NSB, 256, 0, stream>>>(loc, bsum, offs, cursor);
    scatter_kernel<<<NVB * NXCD, BLK, 0, stream>>>(w_rows, w_cols, w_vals,
                                                   cursor, cmeta);

    // ---- iterations ----
    spmm_fused_kernel<true><<<NB_SP4, BLK, 0, stream>>>(offs, cmeta, F_bf, d, V_bf);
    for (int it = 0; it < NITER; ++it) {
        if (it < NITER - 1) {
            wtv_u_kernel<false><<<NB_WT, BLK, 0, stream>>>(offs, cmeta, V_bf,
                                                           F, dm, U, U_bf);
            spmm_fused_kernel<false><<<NB_SP4, BLK, 0, stream>>>(offs, cmeta,
                                                                 U_bf, d, V_bf);
        } else {
            wtv_u_kernel<true><<<NB_WT, BLK, 0, stream>>>(offs, cmeta, V_bf,
                                                          F, dm, U, U_bf);
        }
    }
}

// Round 9
// 788.177 us; speedup vs baseline: 1.1722x; 1.0372x over previous
//
#include <hip/hip_runtime.h>

// NodeDenoisingADMM: N=20000, FEAT=64, K=4, NNZ=320000, NU=2.0, GAMMA=1.0, J=3
// 14 scan iterations, output = final U (N,FEAT) fp32.
//
// State reduction (GAMMA=1): carried state is v alone.
//   S_t = W_k @ U_t ; Y_t = S_t + v_{t-1} ; Z_t = soft(S_t + Y_t, nu_k d)
//   v_t = Y_t - Z_t ; U_{t+1} = (dm*F - sum_k W_k v_k)/(dm+1), dm = d*mask^2
//
// Node-major CSR: rowid = n*K + k. Edge meta packed in 4 B:
//   [31] sign | [30:26] exp5 (bias 96, 0 => value 0) | [25:17] mant9 (RNE)
//   | [16:15] k | [14:0] col       (rel err 2^-11 < bf16 operand err)
// Scatter is XCD-FILTERED (8 buckets by row/2500, block handles bucket
// blockIdx%8) so cursor/cmeta dirty lines live in ONE XCD's L2.
//
// HISTORY: R1 k-phase wtv: REGRESS. R2 meta pipeline: WIN. R3 NT loads:
// REGRESS. R4/R5 deep gather pipeline: REGRESS (VGPR occupancy cliff;
// TLP > ILP). R6 scatter atomic-MLP: REGRESS. R7 two-pass bucket scatter:
// REGRESS (write-amplified rank-scatter). CSR build FROZEN at R2 form.
// R8 spmm SUB-OWNS-ROW: WIN -90us (907->817). Cross-lane plumbing
// (bpermute broadcast + butterfly) was the cost, not memory.
// R9: port the R8 structure to wtv. Tile = 4 nodes; sub owns node n0+sub
// ENTIRELY (whole flat K-span, mean 64 edges) -> no butterfly, segments
// NOT subdivided (avoids R1's failure mode). Cooperative span load
// (<=6 chunks), decode once/lane, skewed LDS table holding the full
// gather index (k*N+col)*16 + fp32 val; sub walks its node via
// ds_read_b64 (16-lane same-slot broadcast). Epilogue wave-wide: 4 subs
// write 4 consecutive nodes = 64 consecutive float4/ushort4 (coalesced;
// R2 wasted 3/4 lanes). KEPT: LAST-only fp32 U store.

constexpr int N_    = 20000;
constexpr int FEAT_ = 64;
constexpr int K_    = 4;
constexpr int NNZ_  = 320000;
constexpr int NF    = N_ * FEAT_;     // 1,280,000
constexpr int KN    = K_ * N_;        // 80,000 CSR rows
constexpr int NEDGE = K_ * NNZ_;      // 1,280,000
constexpr int NITER = 14;
constexpr int BLK   = 256;
constexpr int NSB   = (KN + 255) / 256;  // 313 scan blocks
constexpr int NCPY  = 8;                 // hist privatization copies
constexpr int NXCD  = 8;
constexpr int EPV   = 2048;              // edges per scatter block
constexpr int NVB   = NEDGE / EPV;       // 625 virtual blocks

// spmm4: 3 nodes (tiles) per wave -> 12 CSR rows/wave
constexpr int T_SP  = 3;
constexpr int NW_SP = (N_ + T_SP - 1) / T_SP;             // 6667 waves
constexpr int NB_SP4 = (NW_SP + 3) / 4;                   // 1667 blocks
constexpr int TABSZ = 204;               // 192 slots + skew pad

// wtv4: 4 nodes per wave, sub owns one node's flat span
constexpr int NB_WT4 = ((N_ / 4) + 3) / 4;                // 1250 blocks
constexpr int WCAP  = 384;               // span capacity (mean 256, +8 sigma)
constexpr int TABW  = WCAP + WCAP / 16;  // 408 skewed slots

__constant__ float c_nu[4] = {0.0f, 2.0f, 0.5f, 0.125f};

__device__ __forceinline__ float softf(float x, float t) {
    float a = fabsf(x) - t;
    a = a > 0.0f ? a : 0.0f;
    return copysignf(a, x);
}

__device__ __forceinline__ float bf2f(unsigned short u) {
    union { unsigned int i; float f; } x;
    x.i = ((unsigned int)u) << 16;
    return x.f;
}
__device__ __forceinline__ unsigned short f2bf(float f) {   // RNE
    union { float f; unsigned int i; } x;
    x.f = f;
    unsigned int r = x.i + 0x7FFFu + ((x.i >> 16) & 1u);
    return (unsigned short)(r >> 16);
}

// value bits (fp32) from packed meta
__device__ __forceinline__ unsigned int val_bits(unsigned int p) {
    unsigned int e5 = (p >> 26) & 0x1Fu;
    unsigned int vb = (p & 0x80000000u) | ((e5 + 96u) << 23) |
                      (((p >> 17) & 0x1FFu) << 14);
    return (e5 == 0u) ? 0u : vb;
}

// spmm table entry: low32 = col*16 (ushort4 base), high32 = fp32 val bits
__device__ __forceinline__ unsigned long long enc_tab(unsigned int p) {
    unsigned int c16 = (p & 0x7FFFu) << 4;
    return ((unsigned long long)val_bits(p) << 32) | (unsigned long long)c16;
}

// wtv table entry: low32 = (k*N+col)*16 (full V_bf index), high32 = val
__device__ __forceinline__ unsigned long long enc_wtv(unsigned int p) {
    unsigned int c16 = (((p >> 15) & 3u) * (unsigned int)N_ +
                        (p & 0x7FFFu)) << 4;
    return ((unsigned long long)val_bits(p) << 32) | (unsigned long long)c16;
}

__device__ __forceinline__ void fma4(float4& acc, float v, const ushort4& x) {
    acc.x += v * bf2f(x.x);
    acc.y += v * bf2f(x.y);
    acc.z += v * bf2f(x.z);
    acc.w += v * bf2f(x.w);
}

// ---------------- CSR build + precompute ----------------

// dm[n] = d*mask^2 ; F_bf = bf16(F)
__global__ __launch_bounds__(BLK) void precompute_kernel(
    const float* __restrict__ F, const float* __restrict__ d,
    const float* __restrict__ mask, float* __restrict__ dm,
    unsigned short* __restrict__ F_bf) {
    int i = blockIdx.x * BLK + threadIdx.x;       // over NF/4
    if (i >= NF / 4) return;
    float4 f = ((const float4*)F)[i];
    ushort4 o;
    o.x = f2bf(f.x); o.y = f2bf(f.y); o.z = f2bf(f.z); o.w = f2bf(f.w);
    ((ushort4*)F_bf)[i] = o;
    if ((i & (FEAT_ / 4 - 1)) == 0) {
        int n = i / (FEAT_ / 4);
        dm[n] = d[n] * mask[n] * mask[n];
    }
}

// rowid = rows[e]*K + k ; privatized copies (blockIdx&7)
__global__ __launch_bounds__(BLK) void hist_kernel(
    const int* __restrict__ rows, int* __restrict__ cnt8) {
    int e = blockIdx.x * BLK + threadIdx.x;
    if (e >= NEDGE) return;
    int k = e / NNZ_;
    int copy = blockIdx.x & (NCPY - 1);
    atomicAdd(&cnt8[copy * KN + rows[e] * K_ + k], 1);
}

// block-local exclusive scan over summed copies + block sums
__global__ __launch_bounds__(256) void scan1_kernel(
    const int* __restrict__ cnt8, int* __restrict__ loc,
    int* __restrict__ bsum) {
    int i = blockIdx.x * 256 + threadIdx.x;
    int x = 0;
    if (i < KN) {
        #pragma unroll
        for (int c = 0; c < NCPY; ++c) x += cnt8[c * KN + i];
    }
    int lane = threadIdx.x & 63, wid = threadIdx.x >> 6;
    int v = x;
    #pragma unroll
    for (int off = 1; off < 64; off <<= 1) {
        int t = __shfl_up(v, off, 64);
        if (lane >= off) v += t;
    }
    __shared__ int ws[4];
    if (lane == 63) ws[wid] = v;
    __syncthreads();
    int add = 0;
    for (int u = 0; u < wid; ++u) add += ws[u];
    v += add;
    if (i < KN) loc[i] = v - x;
    if (threadIdx.x == 255) bsum[blockIdx.x] = v;
}

__global__ __launch_bounds__(512) void scan2_kernel(int* __restrict__ bsum) {
    int tid = threadIdx.x;
    int x = (tid < NSB) ? bsum[tid] : 0;
    int lane = tid & 63, wid = tid >> 6;
    int v = x;
    #pragma unroll
    for (int off = 1; off < 64; off <<= 1) {
        int t = __shfl_up(v, off, 64);
        if (lane >= off) v += t;
    }
    __shared__ int ws[8];
    if (lane == 63) ws[wid] = v;
    __syncthreads();
    int add = 0;
    for (int u = 0; u < wid; ++u) add += ws[u];
    v += add;
    if (tid < NSB) bsum[tid] = v - x;
}

__global__ __launch_bounds__(256) void scan3_kernel(
    const int* __restrict__ loc, const int* __restrict__ bsum,
    int* __restrict__ offs, int* __restrict__ cursor) {
    int i = blockIdx.x * 256 + threadIdx.x;
    if (i < KN) {
        int v = loc[i] + bsum[blockIdx.x];
        offs[i] = v;
        cursor[i] = v;
    }
    if (i == 0) offs[KN] = NEDGE;
}

// XCD-filtered scatter (R2 form — frozen; R3/R6/R7 variants all regressed).
__global__ __launch_bounds__(BLK) void scatter_kernel(
    const int* __restrict__ rows, const int* __restrict__ cols,
    const float* __restrict__ vals, int* __restrict__ cursor,
    unsigned int* __restrict__ cmeta) {
    int xcd = blockIdx.x & (NXCD - 1);
    int vb  = blockIdx.x >> 3;
    int ebase = vb * EPV;
    #pragma unroll
    for (int i = 0; i < EPV / BLK; ++i) {
        int e = ebase + i * BLK + threadIdx.x;
        int row = rows[e];
        if (row / (N_ / NXCD) != xcd) continue;
        int k = e / NNZ_;
        unsigned int b  = __float_as_uint(vals[e]);
        unsigned int rb = b + 0x1FFFu + ((b >> 14) & 1u);  // RNE to 9 mant
        int exp8 = (int)((rb >> 23) & 0xFF);
        unsigned int pk = 0u;
        if (exp8 > 96)                                     // else flush to 0
            pk = (b & 0x80000000u) | ((unsigned int)(exp8 - 96) << 26) |
                 (((rb >> 14) & 0x1FFu) << 17);
        pk |= ((unsigned int)k << 15) | (unsigned int)cols[e];
        int pos = atomicAdd(&cursor[row * K_ + k], 1);
        cmeta[pos] = pk;
    }
}

// ---------------- iteration kernels ----------------

// spmm4: wave handles T_SP=3 node-tiles; tile = node n = CSR rows
// n*4+k, k=0..3; sub (lane>>4) == k. Per tile: cooperative meta load of
// the flat span [offs[4n], offs[4n+4]) (1-3 chunks), decode once/lane,
// deposit (col*16, v) into skewed LDS table, then each sub serially walks
// its own row: 1 ds_read_b64 per step (broadcast within sub), gather,
// fma. No bpermute broadcast, no butterfly; epilogue is wave-wide.
// Meta for tile t+1 prefetched (raw u32 regs) before tile t's steps.
// Span >192 overflow handled by a uniform serial loop (never in practice).
template <bool FIRST>
__global__ __launch_bounds__(BLK) void spmm_fused_kernel(
    const int* __restrict__ offs, const unsigned int* __restrict__ cmeta,
    const unsigned short* __restrict__ Xb,
    const float* __restrict__ d, unsigned short* __restrict__ V_bf) {
    __shared__ unsigned long long tab[4][2][TABSZ];
    int wave = (blockIdx.x * BLK + threadIdx.x) >> 6;
    int lane = threadIdx.x & 63;
    int sub  = lane >> 4, q = lane & 15;
    int widx = threadIdx.x >> 6;
    int n0 = wave * T_SP;
    if (n0 >= N_) return;
    int off_l = 0;
    if (lane <= 4 * T_SP) {              // 13 offsets
        int i = n0 * K_ + lane;
        if (i > KN) i = KN;
        off_l = offs[i];
    }
    const ushort4* X4 = (const ushort4*)Xb;
    ushort4* V4 = (ushort4*)V_bf;
    float nu_s = sub == 0 ? 0.0f : (sub == 1 ? 2.0f : (sub == 2 ? 0.5f : 0.125f));

    // prologue: tile 0 span + raw meta
    int tb = __shfl(off_l, 0, 64);
    int te = __shfl(off_l, 4, 64);
    int span = te - tb;
    unsigned int pA = 0, pB = 0, pC = 0;
    if (lane < span)       pA = cmeta[tb + lane];
    if (64 + lane < span)  pB = cmeta[tb + 64 + lane];
    if (128 + lane < span) pC = cmeta[tb + 128 + lane];

    #pragma unroll
    for (int t = 0; t < T_SP; ++t) {
        int n = n0 + t;
        if (n >= N_) break;
        unsigned long long* Tc = tab[widx][t & 1];
        // per-sub window within the span
        int bs = __shfl(off_l, 4 * t + sub, 64);
        int es = __shfl(off_l, 4 * t + sub + 1, 64);
        int pre = bs - tb;
        int cnt = es - bs;
        int jmax = 192 - pre;
        jmax = cnt < jmax ? cnt : jmax;
        if (jmax < 0) jmax = 0;
        int maxc = jmax;
        { int o1 = __shfl_xor(maxc, 16, 64); maxc = maxc > o1 ? maxc : o1;
          int o2 = __shfl_xor(maxc, 32, 64); maxc = maxc > o2 ? maxc : o2; }
        // decode prefetched meta -> skewed LDS table
        if (lane < span)       { int s = lane;       Tc[s + (s >> 4)] = enc_tab(pA); }
        if (64 + lane < span)  { int s = 64 + lane;  Tc[s + (s >> 4)] = enc_tab(pB); }
        if (128 + lane < span) { int s = 128 + lane; Tc[s + (s >> 4)] = enc_tab(pC); }
        // prefetch next tile's raw meta (flies over this tile's steps)
        int tbn = te, ten = te, spann = 0;
        unsigned int nA = 0, nB = 0, nC = 0;
        if (t + 1 < T_SP && n + 1 < N_) {
            ten = __shfl(off_l, 4 * t + 8, 64);
            spann = ten - tbn;
            if (lane < spann)       nA = cmeta[tbn + lane];
            if (64 + lane < spann)  nB = cmeta[tbn + 64 + lane];
            if (128 + lane < spann) nC = cmeta[tbn + 128 + lane];
        }
        // table writes visible before reads (same wave; explicit drain)
        asm volatile("s_waitcnt lgkmcnt(0)" ::: "memory");
        // steps: each sub walks its own row, 4-deep gather batches
        float4 acc = {0.f, 0.f, 0.f, 0.f};
        for (int i0 = 0; i0 < maxc; i0 += 4) {
            float vv[4]; int cc[4];
            #pragma unroll
            for (int u = 0; u < 4; ++u) {
                int j = i0 + u;
                bool ok = j < jmax;
                int slot = ok ? pre + j : 0;
                unsigned long long e = Tc[slot + (slot >> 4)];
                cc[u] = (int)(unsigned int)e;
                vv[u] = ok ? __uint_as_float((unsigned int)(e >> 32)) : 0.0f;
            }
            ushort4 xx[4];
            #pragma unroll
            for (int u = 0; u < 4; ++u) xx[u] = X4[cc[u] + q];
            #pragma unroll
            for (int u = 0; u < 4; ++u) fma4(acc, vv[u], xx[u]);
        }
        // span >192 overflow: uniform serial walk (never in practice)
        if (span > 192) {
            for (int e = tb + 192; e < te; ++e) {
                unsigned int p = cmeta[e];
                int ke = (int)((p >> 15) & 3u);
                unsigned long long en = enc_tab(p);
                if (sub == ke) {
                    ushort4 x = X4[(int)(unsigned int)en + q];
                    fma4(acc, __uint_as_float((unsigned int)(en >> 32)), x);
                }
            }
        }
        // epilogue: wave-wide (each lane owns 4 feats of row (n, k=sub))
        {
            float dn = d[n];
            int idx4 = (sub * N_ + n) * (FEAT_ / 4) + q;
            float thr = nu_s * dn;
            float4 y;
            if (FIRST) {
                y = make_float4(0.f, 0.f, 0.f, 0.f);
            } else {
                ushort4 vp = V4[idx4];
                y.x = acc.x + bf2f(vp.x); y.y = acc.y + bf2f(vp.y);
                y.z = acc.z + bf2f(vp.z); y.w = acc.w + bf2f(vp.w);
            }
            ushort4 o;
            o.x = f2bf(y.x - softf(acc.x + y.x, thr));
            o.y = f2bf(y.y - softf(acc.y + y.y, thr));
            o.z = f2bf(y.z - softf(acc.z + y.z, thr));
            o.w = f2bf(y.w - softf(acc.w + y.w, thr));
            V4[idx4] = o;
        }
        // rotate pipeline state
        tb = tbn; te = ten; span = spann;
        pA = nA; pB = nB; pC = nC;
    }
}

// wtv4 (R9): wave = 4 nodes; sub owns node n0+sub entirely (flat span over
// all k, mean 64 edges — NOT subdivided). Cooperative load of the 4-node
// union span (mean 256, cap 384 = +8 sigma), decode once/lane into skewed
// LDS table with FULL gather index (k*N+col)*16; each sub walks its own
// node 4-deep batched (ds_read_b64 same-slot broadcast). No butterfly.
// Epilogue wave-wide: 64 consecutive float4/ushort4 stores (coalesced).
// U = (dm*F - acc)/(dm+1); fp32 U stored ONLY when LAST; bf16 always.
template <bool LAST>
__global__ __launch_bounds__(BLK) void wtv_u_kernel(
    const int* __restrict__ offs, const unsigned int* __restrict__ cmeta,
    const unsigned short* __restrict__ V_bf,
    const float* __restrict__ F, const float* __restrict__ dm,
    float* __restrict__ U, unsigned short* __restrict__ U_bf) {
    __shared__ unsigned long long tab[4][TABW];
    int wave = (blockIdx.x * BLK + threadIdx.x) >> 6;
    int lane = threadIdx.x & 63;
    int sub  = lane >> 4, q = lane & 15;
    int widx = threadIdx.x >> 6;
    int n0 = wave * 4;
    if (n0 >= N_) return;                // N_ % 4 == 0 -> full tiles only
    int off_l = 0;
    if (lane <= 16) {                    // 17 offsets spanning 4 nodes
        int i = n0 * K_ + lane;
        if (i > KN) i = KN;
        off_l = offs[i];
    }
    const ushort4* V4 = (const ushort4*)V_bf;

    int tb = __shfl(off_l, 0, 64);
    int te = __shfl(off_l, 16, 64);
    int span = te - tb;
    // cooperative raw meta load (up to 6 chunks = 384)
    unsigned int pr[6];
    #pragma unroll
    for (int c = 0; c < 6; ++c) {
        pr[c] = 0u;
        if (c * 64 + lane < span) pr[c] = cmeta[tb + c * 64 + lane];
    }
    // per-sub window = its node's full span
    int bs = __shfl(off_l, 4 * sub, 64);
    int es = __shfl(off_l, 4 * sub + 4, 64);
    int pre = bs - tb;
    int cnt = es - bs;
    int jmax = WCAP - pre;
    jmax = cnt < jmax ? cnt : jmax;
    if (jmax < 0) jmax = 0;
    int maxc = jmax;
    { int o1 = __shfl_xor(maxc, 16, 64); maxc = maxc > o1 ? maxc : o1;
      int o2 = __shfl_xor(maxc, 32, 64); maxc = maxc > o2 ? maxc : o2; }
    // decode -> skewed table
    unsigned long long* Tc = tab[widx];
    #pragma unroll
    for (int c = 0; c < 6; ++c) {
        int s = c * 64 + lane;
        if (s < span) Tc[s + (s >> 4)] = enc_wtv(pr[c]);
    }
    asm volatile("s_waitcnt lgkmcnt(0)" ::: "memory");
    // each sub walks its own node, 4-deep gather batches
    float4 acc = {0.f, 0.f, 0.f, 0.f};
    for (int i0 = 0; i0 < maxc; i0 += 4) {
        float vv[4]; int cc[4];
        #pragma unroll
        for (int u = 0; u < 4; ++u) {
            int j = i0 + u;
            bool ok = j < jmax;
            int slot = ok ? pre + j : 0;
            unsigned long long e = Tc[slot + (slot >> 4)];
            cc[u] = (int)(unsigned int)e;
            vv[u] = ok ? __uint_as_float((unsigned int)(e >> 32)) : 0.0f;
        }
        ushort4 xx[4];
        #pragma unroll
        for (int u = 0; u < 4; ++u) xx[u] = V4[cc[u] + q];
        #pragma unroll
        for (int u = 0; u < 4; ++u) fma4(acc, vv[u], xx[u]);
    }
    // span > WCAP overflow: uniform serial walk (never in practice)
    if (span > WCAP) {
        for (int e = tb + WCAP; e < te; ++e) {
            unsigned int p = cmeta[e];
            unsigned long long en = enc_wtv(p);
            if (e >= bs && e < es) {
                ushort4 x = V4[(int)(unsigned int)en + q];
                fma4(acc, __uint_as_float((unsigned int)(en >> 32)), x);
            }
        }
    }
    // epilogue: wave-wide, node n = n0+sub (64 consecutive float4s)
    {
        int n = n0 + sub;
        float dmv = dm[n];
        float r2 = 1.0f / (dmv + 1.0f);
        int idx4 = n * (FEAT_ / 4) + q;
        float4 f = ((const float4*)F)[idx4];
        float4 o;
        o.x = (dmv * f.x - acc.x) * r2; o.y = (dmv * f.y - acc.y) * r2;
        o.z = (dmv * f.z - acc.z) * r2; o.w = (dmv * f.w - acc.w) * r2;
        if (LAST) ((float4*)U)[idx4] = o;
        ushort4 ob;
        ob.x = f2bf(o.x); ob.y = f2bf(o.y);
        ob.z = f2bf(o.z); ob.w = f2bf(o.w);
        ((ushort4*)U_bf)[idx4] = ob;
    }
}

extern "C" void kernel_launch(void* const* d_in, const int* in_sizes, int n_in,
                              void* d_out, int out_size, void* d_ws, size_t ws_size,
                              hipStream_t stream) {
    const float* F      = (const float*)d_in[0];
    const int*   w_rows = (const int*)d_in[1];
    const int*   w_cols = (const int*)d_in[2];
    const float* w_vals = (const float*)d_in[3];
    const float* d      = (const float*)d_in[4];
    const float* mask   = (const float*)d_in[5];
    float* U = (float*)d_out;

    // workspace layout (~29 MB)
    unsigned int* cmeta  = (unsigned int*)d_ws;               // NEDGE u32
    unsigned short* V_bf = (unsigned short*)(cmeta + NEDGE);  // KN*FEAT us
    unsigned short* U_bf = V_bf + (size_t)KN * FEAT_;         // NF us
    unsigned short* F_bf = U_bf + NF;                         // NF us
    float* dm     = (float*)(F_bf + NF);                      // N
    int*   cnt8   = (int*)(dm + N_);                          // NCPY*KN
    int*   loc    = cnt8 + NCPY * KN;                         // KN
    int*   bsum   = loc + KN;                                 // pad 512
    int*   offs   = bsum + 512;                               // KN+1
    int*   cursor = offs + KN + 1;                            // KN

    const int gEdge = NEDGE / BLK;                // 5000
    const int gNF4  = (NF / 4) / BLK;             // 1250

    // ---- CSR build + precompute ----
    hipMemsetAsync(cnt8, 0, (size_t)NCPY * KN * 4, stream);
    precompute_kernel<<<gNF4, BLK, 0, stream>>>(F, d, mask, dm, F_bf);
    hist_kernel<<<gEdge, BLK, 0, stream>>>(w_rows, cnt8);
    scan1_kernel<<<NSB, 256, 0, stream>>>(cnt8, loc, bsum);
    scan2_kernel<<<1, 512, 0, stream>>>(bsum);
    scan3_kernel<<<NSB, 256, 0, stream>>>(loc, bsum, offs, cursor);
    scatter_kernel<<<NVB * NXCD, BLK, 0, stream>>>(w_rows, w_cols, w_vals,
                                                   cursor, cmeta);

    // ---- iterations ----
    spmm_fused_kernel<true><<<NB_SP4, BLK, 0, stream>>>(offs, cmeta, F_bf, d, V_bf);
    for (int it = 0; it < NITER; ++it) {
        if (it < NITER - 1) {
            wtv_u_kernel<false><<<NB_WT4, BLK, 0, stream>>>(offs, cmeta, V_bf,
                                                            F, dm, U, U_bf);
            spmm_fused_kernel<false><<<NB_SP4, BLK, 0, stream>>>(offs, cmeta,
                                                                 U_bf, d, V_bf);
        } else {
            wtv_u_kernel<true><<<NB_WT4, BLK, 0, stream>>>(offs, cmeta, V_bf,
                                                           F, dm, U, U_bf);
        }
    }
}